// Round 4
// baseline (375.570 us; speedup 1.0000x reference)
//
#include <hip/hip_runtime.h>
#include <hip/hip_bf16.h>

// EmbeddingBagList: T=26, V=1000, D=128, B=8192, NNZ=409600, mode=sum, fp32.
// Round-9: round-8 (MFMA segmented-sum + global_load_lds staging, verified) with
// the per-batch vmcnt(0) DRAIN replaced by a double-buffered counted-vmcnt
// pipeline (T3/T4). Round-8 was latency-bound: issue 8 DMAs -> vmcnt(0) ->
// compute exposed the full L2-gather latency every 32-row batch (17.4 B/cyc/CU
// vs the ~2.3 lane-txn/cyc/CU this problem has demonstrated). Now each wave has
// two 8KB LDS buffers; steady state keeps 8-17 vmem ops in flight:
//   [idx_next load][DMAs batch(w,1)] vmcnt(9) compute(w,0)
//   [DMAs batch(w+1,0)]              vmcnt(8) compute(w,1)
// Counted waits are exact per-branch (two/next_w variants: 9/8/1/0). WAR on a
// buffer is safe: each COMPUTE retires its tr-reads (lgkmcnt(0)) before the
// buffer is re-issued. Compute path (tr-read addressing, A-mask, MFMA, D-store)
// is byte-identical to the verified round-8.

#define T_ 26
#define V_ 1000
#define VP_ 1001          // padded rows: row V_ is an all-zero sentinel
#define D_ 128
#define B_ 8192
#define NNZ_ 409600

typedef short s4v  __attribute__((ext_vector_type(4)));
typedef short s8v  __attribute__((ext_vector_type(8)));
typedef float f32x4 __attribute__((ext_vector_type(4)));
typedef unsigned int u32x4v __attribute__((ext_vector_type(4)));

__device__ __forceinline__ unsigned short f2bf(float f) {
    __hip_bfloat16 b = __float2bfloat16(f);   // RNE
    return *reinterpret_cast<unsigned short*>(&b);
}

// ---- pre-pass: fp32 weights -> bf16 rows in workspace (+ zero sentinel row) ----
__global__ __launch_bounds__(256) void convert_kernel(
    const float* __restrict__ weights, uint4* __restrict__ wbf)
{
    const int u = blockIdx.x * 256 + threadIdx.x;   // one uint4 (8 dims) per thread
    const int total = T_ * VP_ * 16;
    if (u >= total) return;
    const int s  = u & 15;              // 16B slot in row
    const int rv = (u >> 4) % VP_;      // padded row
    const int t  = u / (VP_ * 16);      // table
    uint4 pk = make_uint4(0u, 0u, 0u, 0u);
    if (rv < V_) {
        const float* src = weights + ((size_t)t * V_ + rv) * D_ + s * 8;
        const float4 a = ((const float4*)src)[0];
        const float4 b = ((const float4*)src)[1];
        pk.x = ((unsigned)f2bf(a.y) << 16) | f2bf(a.x);
        pk.y = ((unsigned)f2bf(a.w) << 16) | f2bf(a.z);
        pk.z = ((unsigned)f2bf(b.y) << 16) | f2bf(b.x);
        pk.w = ((unsigned)f2bf(b.w) << 16) | f2bf(b.z);
    }
    wbf[u] = pk;
}

// hardware transpose-read: group of 16 lanes, addr = tile_base + s*8 (linear),
// delivers column s of the [4][16] row-major bf16 tile to lane s.
#define TRRD(dst, addr, OFFLIT) \
    asm volatile("ds_read_b64_tr_b16 %0, %1 offset:" OFFLIT : "=v"(dst) : "v"(addr))

#define MFMA16(a, b, c) __builtin_amdgcn_mfma_f32_16x16x32_bf16((a), (b), (c), 0, 0, 0)
#define CAT8(lo, hi) __builtin_shufflevector((lo), (hi), 0, 1, 2, 3, 4, 5, 6, 7)

// issue 8 gather-DMAs (32 rows x 256B) into LDS buffer at lds_base + BUFOFS
#define ISSUE(BUFOFS, IDX, KB) do {                                              \
    _Pragma("unroll")                                                            \
    for (int j_ = 0; j_ < 8; ++j_) {                                             \
        const int bb_ = __shfl((IDX), (KB) + 4 * j_ + r4);                       \
        const uint4* gp_ = wt + (size_t)bb_ * 16 + sl;                           \
        __builtin_amdgcn_global_load_lds(                                        \
            (const __attribute__((address_space(1))) void*)gp_,                  \
            (__attribute__((address_space(3))) void*)(uintptr_t)(lds_base + (BUFOFS) + (unsigned)(j_ * 1024)), \
            16, 0, 0);                                                           \
    }                                                                            \
} while (0)

#define WAITVM(NLIT) do {                                                        \
    asm volatile("s_waitcnt vmcnt(" #NLIT ")" ::: "memory");                     \
    __builtin_amdgcn_sched_barrier(0);                                           \
} while (0)

// compute one 32-row batch: A-mask + 16 tr-reads + 8 MFMAs (verified round-8)
#define COMPUTE(RA, PB) do {                                                     \
    const int rel_ = (PB) + q * 8 - lo;                                          \
    u32x4v mu_;                                                                  \
    _Pragma("unroll")                                                            \
    for (int pr_ = 0; pr_ < 4; ++pr_) {                                          \
        const unsigned a0_ = ((unsigned)(rel_ + 2 * pr_)     < ulen) ? 0x00003F80u : 0u; \
        const unsigned a1_ = ((unsigned)(rel_ + 2 * pr_ + 1) < ulen) ? 0x3F800000u : 0u; \
        mu_[pr_] = a0_ | a1_;                                                    \
    }                                                                            \
    const s8v amask_ = __builtin_bit_cast(s8v, mu_);                             \
    s4v u0, u1, u2, u3, u4, u5, u6, u7;                                          \
    TRRD(u0, (RA), "0");    TRRD(u1, (RA), "1024");                              \
    TRRD(u2, (RA), "128");  TRRD(u3, (RA), "1152");                              \
    TRRD(u4, (RA), "256");  TRRD(u5, (RA), "1280");                              \
    TRRD(u6, (RA), "384");  TRRD(u7, (RA), "1408");                              \
    asm volatile("s_waitcnt lgkmcnt(0)" ::: "memory");                           \
    __builtin_amdgcn_sched_barrier(0);                                           \
    acc[0] = MFMA16(amask_, CAT8(u0, u1), acc[0]);                               \
    acc[1] = MFMA16(amask_, CAT8(u2, u3), acc[1]);                               \
    acc[2] = MFMA16(amask_, CAT8(u4, u5), acc[2]);                               \
    acc[3] = MFMA16(amask_, CAT8(u6, u7), acc[3]);                               \
    TRRD(u0, (RA), "512");  TRRD(u1, (RA), "1536");                              \
    TRRD(u2, (RA), "640");  TRRD(u3, (RA), "1664");                              \
    TRRD(u4, (RA), "768");  TRRD(u5, (RA), "1792");                              \
    TRRD(u6, (RA), "896");  TRRD(u7, (RA), "1920");                              \
    asm volatile("s_waitcnt lgkmcnt(0)" ::: "memory");                           \
    __builtin_amdgcn_sched_barrier(0);                                           \
    acc[4] = MFMA16(amask_, CAT8(u0, u1), acc[4]);                               \
    acc[5] = MFMA16(amask_, CAT8(u2, u3), acc[5]);                               \
    acc[6] = MFMA16(amask_, CAT8(u4, u5), acc[6]);                               \
    acc[7] = MFMA16(amask_, CAT8(u6, u7), acc[7]);                               \
} while (0)

__global__ __launch_bounds__(256, 2) void embag_mfma_kernel(
    const uint4* __restrict__ wbf,       // [T, VP_, 16] bf16 rows
    const int*   __restrict__ indices,   // [T, NNZ]
    const int*   __restrict__ offsets,   // [T, B]
    float*       __restrict__ out)       // [T, B, D]
{
    // 16 KB per wave: two 8KB batch buffers (64 tiles of [4 rows][16 dims] each)
    __shared__ uint4 smem4[4 * 1024];

    const int bid   = blockIdx.x;
    const int xcd   = bid & 7;        // dispatch round-robins blocks over 8 XCDs
    const int r_    = bid >> 3;
    const int tslot = r_ & 3;
    const int chunk = r_ >> 2;        // 0..127
    const int t     = xcd + 8 * tslot;
    if (t >= T_) return;

    const int wave = threadIdx.x >> 6;
    const int lane = threadIdx.x & 63;
    const int q    = lane >> 4;       // MFMA lane group 0..3
    const int s    = lane & 15;       // MFMA lane-in-group 0..15

    // gather roles: lane writes LDS byte lane*16 (+ j*1024) = tile byte
    // c*128 + r4*32 + h*16  ->  c = lane>>3, r4 = (lane>>1)&3, h = lane&1.
    const int r4 = (lane >> 1) & 3;                 // row-within-quad this lane loads
    const int sl = ((lane >> 3) << 1) | (lane & 1); // 16B slot (dims 8*sl..8*sl+7)

    const int grp = chunk * 4 + wave; // 0..511
    const int g0  = grp * 16;         // first bag of this wave's 16-bag group

    // bag boundaries: lane i (=s) owns bag g0+i with range [lo, hi)
    const int* off = offsets + t * B_;
    const int oi = g0 + lane;
    int o_l = 0;
    if (lane <= 16) o_l = (oi < B_) ? off[oi] : NNZ_;   // off[B_] := NNZ_
    const int lo       = __shfl(o_l, s);
    const int hi       = __shfl(o_l, s + 1);
    const unsigned ulen = (unsigned)(hi - lo);
    const int wstart   = __shfl(o_l, 0);
    const int wend     = __shfl(o_l, 16);

    const uint4* wt  = wbf + (size_t)t * VP_ * 16;
    const int*   ind = indices + (size_t)t * NNZ_;

    // LDS addresses (low-32 of generic pointer = LDS byte offset; validated r7)
    const unsigned lds_base = ((unsigned)(uintptr_t)(&smem4[0])) + (wave << 14);
    const unsigned ra0 = lds_base + (q << 11) + (s << 3);   // buf0 tr-read base
    const unsigned ra1 = ra0 + 8192u;                       // buf1 tr-read base

    f32x4 acc[8];
    #pragma unroll
    for (int c = 0; c < 8; ++c) acc[c] = f32x4{0.f, 0.f, 0.f, 0.f};

    // ---- prologue: load window-0 indices, issue batch(0,0) into buf0 ----
    int myidx;
    {
        const int p = wstart + lane;
        myidx = (p < NNZ_) ? ind[p] : V_;   // sentinel beyond table end
    }
    ISSUE(0u, myidx, 0);

    int wb = wstart;
    for (;;) {
        const bool two    = (wend - wb) > 32;   // window has a second batch
        const bool next_w = (wb + 64) < wend;   // another window follows

        int myidx_next = V_;
        if (next_w) {
            const int pn = wb + 64 + lane;
            myidx_next = (pn < NNZ_) ? ind[pn] : V_;
        }
        __builtin_amdgcn_sched_barrier(0);      // pin idx load before the DMAs

        if (two) {
            ISSUE(8192u, myidx, 32);            // batch(w,1) -> buf1
            if (next_w) {
                // outstanding: [8 b(w,0)][1 idx][8 b(w,1)] -> complete oldest 8
                WAITVM(9);
                COMPUTE(ra0, wb);
                ISSUE(0u, myidx_next, 0);       // batch(w+1,0) -> buf0
                // outstanding: [8 b(w,1)][8 b(w+1,0)] -> complete b(w,1)
                WAITVM(8);
                COMPUTE(ra1, wb + 32);
            } else {
                WAITVM(8);                      // [8 b(w,0)][8 b(w,1)]
                COMPUTE(ra0, wb);
                WAITVM(0);
                COMPUTE(ra1, wb + 32);
            }
        } else {
            if (next_w) {
                WAITVM(1);                      // [8 b(w,0)][1 idx]
                COMPUTE(ra0, wb);
                ISSUE(0u, myidx_next, 0);       // batch(w+1,0) -> buf0
            } else {
                WAITVM(0);
                COMPUTE(ra0, wb);
            }
        }

        if (!next_w) break;
        wb += 64;
        myidx = myidx_next;
    }

    // D layout (m89): col = lane&15 (dim-in-chunk), row = (lane>>4)*4 + reg (bag)
    float* outt = out + ((size_t)t * B_ + g0) * D_;
    #pragma unroll
    for (int c = 0; c < 8; ++c) {
        #pragma unroll
        for (int r2 = 0; r2 < 4; ++r2) {
            outt[(size_t)(q * 4 + r2) * D_ + c * 16 + s] = acc[c][r2];
        }
    }
}

// ---- fallback: round-3 fp32 gather (used only if ws_size is too small) ----
__global__ __launch_bounds__(256) void embag_fp32_kernel(
    const float* __restrict__ weights,
    const int*   __restrict__ indices,
    const int*   __restrict__ offsets,
    float*       __restrict__ out)
{
    const int bid   = blockIdx.x;
    const int xcd   = bid & 7;
    const int r     = bid >> 3;
    const int tslot = r & 3;
    const int chunk = r >> 2;
    const int t     = xcd + 8 * tslot;
    if (t >= T_) return;

    const int wave = threadIdx.x >> 6;
    const int lane = threadIdx.x & 63;
    const int bag  = chunk * 4 + wave;

    const int* off = offsets + t * B_;
    const int start = off[bag];
    const int end   = (bag == B_ - 1) ? NNZ_ : off[bag + 1];

    const float* wt  = weights + (size_t)t * V_ * D_;
    const int*   ind = indices + (size_t)t * NNZ_;

    const int half  = lane >> 5;
    const int dl    = lane & 31;
    const int col   = dl * 4;
    const int lbase = half << 5;

    float4 acc0 = make_float4(0.f, 0.f, 0.f, 0.f);
    float4 acc1 = make_float4(0.f, 0.f, 0.f, 0.f);

    for (int base = start; base < end; base += 64) {
        const int cnt = (end - base < 64) ? (end - base) : 64;
        const int rowload = (dl << 1) + half;
        int myidx = 0;
        if (rowload < cnt) myidx = ind[base + rowload];
        const int nk = (cnt - half + 1) >> 1;
        int k = 0;
        for (; k + 3 < nk; k += 4) {
            const int i0 = __shfl(myidx, lbase + k);
            const int i1 = __shfl(myidx, lbase + k + 1);
            const int i2 = __shfl(myidx, lbase + k + 2);
            const int i3 = __shfl(myidx, lbase + k + 3);
            const float4 r0 = *(const float4*)(wt + (size_t)i0 * D_ + col);
            const float4 r1 = *(const float4*)(wt + (size_t)i1 * D_ + col);
            const float4 r2 = *(const float4*)(wt + (size_t)i2 * D_ + col);
            const float4 r3 = *(const float4*)(wt + (size_t)i3 * D_ + col);
            acc0.x += r0.x; acc0.y += r0.y; acc0.z += r0.z; acc0.w += r0.w;
            acc1.x += r1.x; acc1.y += r1.y; acc1.z += r1.z; acc1.w += r1.w;
            acc0.x += r2.x; acc0.y += r2.y; acc0.z += r2.z; acc0.w += r2.w;
            acc1.x += r3.x; acc1.y += r3.y; acc1.z += r3.z; acc1.w += r3.w;
        }
        for (; k < nk; ++k) {
            const int i0 = __shfl(myidx, lbase + k);
            const float4 r0 = *(const float4*)(wt + (size_t)i0 * D_ + col);
            acc0.x += r0.x; acc0.y += r0.y; acc0.z += r0.z; acc0.w += r0.w;
        }
    }

    float4 acc;
    acc.x = acc0.x + acc1.x; acc.y = acc0.y + acc1.y;
    acc.z = acc0.z + acc1.z; acc.w = acc0.w + acc1.w;
    acc.x += __shfl_down(acc.x, 32, 64);
    acc.y += __shfl_down(acc.y, 32, 64);
    acc.z += __shfl_down(acc.z, 32, 64);
    acc.w += __shfl_down(acc.w, 32, 64);
    if (half == 0)
        *(float4*)(out + ((size_t)t * B_ + bag) * D_ + col) = acc;
}

extern "C" void kernel_launch(void* const* d_in, const int* in_sizes, int n_in,
                              void* d_out, int out_size, void* d_ws, size_t ws_size,
                              hipStream_t stream) {
    const float* weights = (const float*)d_in[0];
    const int*   indices = (const int*)d_in[1];
    const int*   offsets = (const int*)d_in[2];
    float*       out     = (float*)d_out;

    const size_t ws_needed = (size_t)T_ * VP_ * 16 * sizeof(uint4);  // 6.66 MB

    if (ws_size >= ws_needed) {
        uint4* wbf = (uint4*)d_ws;
        const int conv_total  = T_ * VP_ * 16;
        const int conv_blocks = (conv_total + 255) / 256;
        convert_kernel<<<conv_blocks, 256, 0, stream>>>(weights, wbf);
        // 8 xcd-slots x 4 table-slots x 128 group-chunks; 4 waves/block, 16 bags/wave
        embag_mfma_kernel<<<8 * 4 * 128, 256, 0, stream>>>(wbf, indices, offsets, out);
    } else {
        embag_fp32_kernel<<<8 * 4 * (B_ / 4), 256, 0, stream>>>(weights, indices, offsets, out);
    }
}

// Round 6
// 266.797 us; speedup vs baseline: 1.4077x; 1.4077x over previous
//
#include <hip/hip_runtime.h>
#include <hip/hip_bf16.h>

// EmbeddingBagList: T=26, V=1000, D=128, B=8192, NNZ=409600, mode=sum, fp32.
// Round-11: LDS-RESIDENT TABLE. r3/r4/r8/r9 all saturate at ~55cy per 64-lane
// scattered VMEM gather instr (0.017-0.019 instr/cy/CU across fp32/bf16/DMA
// variants) -> the scattered-VMEM path is the wall. Row reuse is 410x, and a
// dim-quarter slab (1000 x 32dims bf16 = 64,064B incl. sentinel) fits static
// LDS. So: each block owns (table t, dim-quarter dq) + 1664 bags; fills the
// slab once (fp32->bf16 inline, no d_ws, no convert prepass), then gathers
// rows DIRECTLY from LDS into MFMA B-fragments via ds_read_b64_tr_b16 with
// per-lane scattered row addresses (r7-verified model: group lane m supplies
// rowbase(m>>2) + (m&3)*8; here rowbase = idx*64, scattered). Segmented-sum
// MFMA core (A = 0/1 mask, K=32 intrinsic) verbatim from verified r7/r9.
// Swizzle: 32B granules XOR'd by row bit1 (bit5 of offset); with the natural
// 16*(r&1) bank-phase of 64B rows, random rows spread over 4 bank-octets ->
// ~4 words/bank = near the b64 structural floor.

#define T_ 26
#define V_ 1000
#define D_ 128
#define B_ 8192
#define NNZ_ 409600

#define NBLK_ 512
#define BPB_ 1664          // bags per block: 104 units * 8192 / 512

typedef short s4v  __attribute__((ext_vector_type(4)));
typedef short s8v  __attribute__((ext_vector_type(8)));
typedef float f32x4 __attribute__((ext_vector_type(4)));
typedef unsigned int u32x4v __attribute__((ext_vector_type(4)));

__device__ __forceinline__ unsigned short f2bf(float f) {
    __hip_bfloat16 b = __float2bfloat16(f);   // RNE
    return *reinterpret_cast<unsigned short*>(&b);
}

// hardware transpose-read, per-lane address (verified r7): in a 16-lane group,
// lane m's 8B fetch at addr[m] lands as elements: out[s][j] <- addr[4j+(s>>2)]
// + 2*(s&3). With addr[m] = rowbase(row m>>2) + (m&3)*8, lane s receives
// column s (dim) of 4 rows -> B-fragment.
#define TRRD(dst, addr) \
    asm volatile("ds_read_b64_tr_b16 %0, %1" : "=v"(dst) : "v"(addr))

#define MFMA32(a, b, c) __builtin_amdgcn_mfma_f32_16x16x32_bf16((a), (b), (c), 0, 0, 0)
#define CAT8(lo, hi) __builtin_shufflevector((lo), (hi), 0, 1, 2, 3, 4, 5, 6, 7)

__global__ __launch_bounds__(1024, 4) void embag_lds_kernel(
    const float* __restrict__ weights,   // [T, V, D] fp32
    const int*   __restrict__ indices,   // [T, NNZ]
    const int*   __restrict__ offsets,   // [T, B]
    float*       __restrict__ out)       // [T, B, D]
{
    // slab: 1001 rows x 64B (32 dims bf16); row 1000 = zero sentinel.
    // granule = 8B; within-row granule gi stored at gi ^ (((r>>1)&1)<<2).
    __shared__ uint2 lds_tab[1001 * 8];

    const int tid  = threadIdx.x;
    const int wave = tid >> 6;        // 0..15
    const int lane = tid & 63;
    const int q    = lane >> 4;       // MFMA lane group
    const int s    = lane & 15;       // lane-in-group (also addr-lane m)
    const int u8o  = (lane & 3) * 8;  // (m&3)*8 within-row u-offset
    const int selbase = 8 * q + (s >> 2);   // batch-row this lane addresses (h=0)

    const unsigned tb = (unsigned)(uintptr_t)(&lds_tab[0]);  // low-32 = LDS offset

    int gb = blockIdx.x * BPB_;           // global bag index (unit-major)
    const int gb_end = gb + BPB_;

    while (gb < gb_end) {
        const int un = gb / 8192;         // unit = (t, dq)
        const int t  = un >> 2;
        const int dq = un & 3;
        const int ue = ((un + 1) * 8192 < gb_end) ? (un + 1) * 8192 : gb_end;

        __syncthreads();                  // previous-slab readers done
        // ---- fill slab (fp32 -> bf16, swizzled); sentinel row zeros ----
        for (int e = tid; e < 1001 * 8; e += 1024) {
            const int r  = e >> 3;
            const int gi = e & 7;
            uint2 pk = make_uint2(0u, 0u);
            if (r < V_) {
                const float4 a = *(const float4*)(
                    weights + ((size_t)t * V_ + r) * D_ + dq * 32 + gi * 4);
                pk.x = ((unsigned)f2bf(a.y) << 16) | f2bf(a.x);
                pk.y = ((unsigned)f2bf(a.w) << 16) | f2bf(a.z);
            }
            const int so = gi ^ (((r >> 1) & 1) << 2);
            lds_tab[r * 8 + so] = pk;
        }
        __syncthreads();

        // ---- process this unit's 16-bag groups (boundaries are 16-aligned) ----
        const int ga = (gb - un * 8192) >> 4;
        const int ge = (ue - un * 8192) >> 4;
        const int* off = offsets + t * B_;
        const int* ind = indices + (size_t)t * NNZ_;
        float* outq = out + (size_t)t * B_ * D_ + dq * 32;

        for (int grp = ga + wave; grp < ge; grp += 16) {
            const int g0 = grp * 16;
            const int oi = g0 + lane;
            int o_l = 0;
            if (lane <= 16) o_l = (oi < B_) ? off[oi] : NNZ_;  // off[B_] := NNZ_
            const int lo     = __shfl(o_l, s);
            const int hi     = __shfl(o_l, s + 1);
            const unsigned ulen = (unsigned)(hi - lo);
            const int wstart = __shfl(o_l, 0);
            const int wend   = __shfl(o_l, 16);

            f32x4 acc0 = {0.f, 0.f, 0.f, 0.f};
            f32x4 acc1 = {0.f, 0.f, 0.f, 0.f};

            for (int wb = wstart; wb < wend; wb += 64) {
                const int p = wb + lane;
                const int myidx = (p < NNZ_) ? ind[p] : V_;   // sentinel past end

                for (int kb = 0; kb < 64 && wb + kb < wend; kb += 32) {
                    const int pb = wb + kb;
                    // scattered row addresses for this lane's tr-read role
                    const int r0 = __shfl(myidx, kb + selbase);       // rows +0..3
                    const int r1 = __shfl(myidx, kb + selbase + 4);   // rows +4..7
                    const unsigned b0 = tb + ((unsigned)r0 << 6) + u8o;
                    const unsigned b1 = tb + ((unsigned)r1 << 6) + u8o;
                    const unsigned cs0 = (((unsigned)r0 >> 1) << 5) & 32u;
                    const unsigned cs1 = (((unsigned)r1 >> 1) << 5) & 32u;
                    const unsigned a00 = b0 + cs0;            // chunk c=0 (dims 0-15)
                    const unsigned a01 = b0 + (32u ^ cs0);    // chunk c=1 (dims 16-31)
                    const unsigned a10 = b1 + cs1;
                    const unsigned a11 = b1 + (32u ^ cs1);

                    // A mask: A[i=s][k=8q+e] = (lo <= pb+8q+e < hi)  (r7-verified)
                    const int rel = pb + q * 8 - lo;
                    u32x4v mu;
                    #pragma unroll
                    for (int pr = 0; pr < 4; ++pr) {
                        const unsigned m0 = ((unsigned)(rel + 2 * pr)     < ulen) ? 0x00003F80u : 0u;
                        const unsigned m1 = ((unsigned)(rel + 2 * pr + 1) < ulen) ? 0x3F800000u : 0u;
                        mu[pr] = m0 | m1;
                    }
                    const s8v amask = __builtin_bit_cast(s8v, mu);

                    s4v u00, u01, u10, u11;
                    TRRD(u00, a00); TRRD(u10, a10);
                    TRRD(u01, a01); TRRD(u11, a11);
                    asm volatile("s_waitcnt lgkmcnt(0)" ::: "memory");
                    __builtin_amdgcn_sched_barrier(0);
                    acc0 = MFMA32(amask, CAT8(u00, u10), acc0);
                    acc1 = MFMA32(amask, CAT8(u01, u11), acc1);
                }
            }

            // D layout (m89): col = s (dim-in-chunk), row = q*4 + reg (bag)
            float* outt = outq + (size_t)g0 * D_;
            #pragma unroll
            for (int r2 = 0; r2 < 4; ++r2) {
                outt[(size_t)(q * 4 + r2) * D_ + s]      = acc0[r2];
                outt[(size_t)(q * 4 + r2) * D_ + 16 + s] = acc1[r2];
            }
        }
        gb = ue;
    }
}

extern "C" void kernel_launch(void* const* d_in, const int* in_sizes, int n_in,
                              void* d_out, int out_size, void* d_ws, size_t ws_size,
                              hipStream_t stream) {
    const float* weights = (const float*)d_in[0];
    const int*   indices = (const int*)d_in[1];
    const int*   offsets = (const int*)d_in[2];
    float*       out     = (float*)d_out;
    (void)d_ws; (void)ws_size;

    // 512 uniform blocks x 1664 bags over 104 (table, dim-quarter) units;
    // single kernel, no workspace, no prepass.
    embag_lds_kernel<<<NBLK_, 1024, 0, stream>>>(weights, indices, offsets, out);
}